// Round 15
// baseline (141.828 us; speedup 1.0000x reference)
//
#include <hip/hip_runtime.h>
#include <stdint.h>

typedef __bf16 bf16_t;
typedef __bf16 bf16x8 __attribute__((ext_vector_type(8)));
typedef float  f32x4  __attribute__((ext_vector_type(4)));
typedef float  f32x16 __attribute__((ext_vector_type(16)));

// LDS: Ab0 [0,4096) Ab1 [4096,8192); epilogue reduce (16KB) unions from 0
#define LDS_TOTAL 16384

// ---------------- weight repack, step-major + kh-major inner layout (R13/R14-verified) ----------------
// Wf2[s][kh][o][j]  (s=0..323, kh=0..1, o=0..63, j=0..7); element = s*1024 + kh*512 + o*8 + j
//   spline s<288: q=s/9, tap=s%9, c=q*2+kh, f=c*9+tap, v = sw[(o*576+f)*8+j]*ss[o*576+f]
//   silu  s>=288: cq=(s-288)/9, tap=(s-288)%9, c=cq*16+kh*8+j, f=c*9+tap, v = bw[o*576+f]
__global__ __launch_bounds__(256) void prep_w_kernel(
    const float* __restrict__ bw, const float* __restrict__ sw,
    const float* __restrict__ ss, bf16_t* __restrict__ Wf2) {
  int idx = blockIdx.x * 256 + threadIdx.x;   // < 324*1024 = 331776
  int j = idx & 7, o = (idx >> 3) & 63, kh = (idx >> 9) & 1, s = idx >> 10;
  int kk = kh * 8 + j;
  float v;
  if (s < 288) {
    int q = s / 9, tap = s - q * 9;
    int c = q * 2 + kh;
    int f = c * 9 + tap;
    v = sw[(o * 576 + f) * 8 + j] * ss[o * 576 + f];
  } else {
    int t2 = s - 288;
    int cq = t2 / 9, tap = t2 - cq * 9;
    int c = cq * 16 + kk;
    int f = c * 9 + tap;
    v = bw[o * 576 + f];
  }
  Wf2[idx] = (bf16_t)v;
}

// ---------------- main fused kernel: grid K-split, A in LDS, B in registers ----------------
// grid 1024 = 8 img x 64 px-tiles x 2 K-halves (channel-pair parity p).
// block = 64 px (8x8) x 64 och, 18 chunks; 4 waves, tap-split {0,1}{2,3}{4,5}{6,7,8}.
// Epilogue: 3-round 16KB LDS reduce, then wave 0 atomicAdds into zeroed out.
__global__ __launch_bounds__(256, 3) void convkan_kernel(
    const float* __restrict__ X, const bf16_t* __restrict__ Wf2,
    float* __restrict__ out) {
  extern __shared__ char smraw[];
  char* const Ab0 = smraw;
  char* const Ab1 = smraw + 4096;

  const int t    = threadIdx.x;
  const int lane = t & 63;
  const int w    = t >> 6;        // wave 0..3 (tap group)

  const int b   = blockIdx.x;
  const int rb  = ((b & 7) << 7) | (b >> 3);   // XCD-chunked (1024%8==0, bijective)
  const int img = rb >> 7;
  const int rem = rb & 127;
  const int p   = rem & 1;        // K-half parity
  const int tile = rem >> 1;
  const int ohb = tile >> 3, owb = tile & 7;

  // ---- A staging geometry: thread -> (channel-half h, halo cell) on 10x12 grid ----
  const int h   = t >> 7;
  const int idx = t & 127;
  const int row = idx / 12, col = idx - row * 12;
  const bool valid = (idx < 120) && (col < 10);
  const int ih = ohb * 8 + row - 1;
  const int iw = owb * 8 + col - 1;
  const bool inb = valid && ((unsigned)ih < 64u) && ((unsigned)iw < 64u);
  const float* Ximg = X + (((size_t)img * 64) << 12);
  const int   psafe = inb ? ((ih << 6) + iw) : 0;   // clamped: loads always issue
  const float xmask = inb ? 1.0f : 0.0f;

  // ---- compute-read geometry (verified R9-R14 12-wide conventions) ----
  const int r    = lane & 31;
  const int kh   = lane >> 5;
  const int khq  = kh * 128;
  const int pb0  = (r >> 3) * 12 + (r & 7);
  const int pb1  = pb0 + 48;
  const int tap0 = (w < 3) ? (w * 2) : 6;
  const int ntap = (w < 3) ? 2 : 3;

  const float G0 = -2.2f, G1 = 2.2f, INVH = 2.5f;

  f32x16 acc[2][2];
  #pragma unroll
  for (int a = 0; a < 2; ++a)
    #pragma unroll
    for (int c = 0; c < 2; ++c) acc[a][c] = (f32x16)0.0f;

  float xP[8], xQ[8];
  bf16x8 BP[3][2], BQ[3][2];      // per-tap B frags, double-buffered (static idx only)

  // logical chunk id for local index k (0..17): spline pairs 2k+p, then silu quads
  auto CS = [&](int k) { return (k < 16) ? (2 * k + p) : (32 + 2 * (k - 16) + p); };

  auto XLOAD = [&](int cs, float* xr) {
    if (cs < 32) {
      xr[0] = Ximg[(((size_t)(2 * cs + h)) << 12) + psafe] * xmask;   // 1 load
    } else {
      const int c0 = (cs - 32) * 16 + h * 8;
      #pragma unroll
      for (int j = 0; j < 8; ++j)                                      // 8 loads
        xr[j] = Ximg[(((size_t)(c0 + j)) << 12) + psafe] * xmask;
    }
  };

  // per-lane coalesced B loads: element = s*1024 + kh*512 + r*8 (+256 for och-tile 1)
  auto BLOAD = [&](int cs, bf16x8 (*BB)[2]) {
    const int sb = (cs < 32) ? cs * 9 : 288 + (cs - 32) * 9;
    #pragma unroll
    for (int tt = 0; tt < 3; ++tt) if (tt < ntap) {
      const bf16_t* pp = Wf2 + (((size_t)(sb + tap0 + tt)) << 10) + (kh << 9) + (r << 3);
      BB[tt][0] = *(const bf16x8*)pp;
      BB[tt][1] = *(const bf16x8*)(pp + 256);
    }
  };

  auto WINW = [&](int cs, const float* xr, char* abuf) {
    if (cs < 32) {
      // uniform cubic B-spline window (verified R1-R14)
      float x  = xr[0];
      float tt = (x - G0) * INVH;
      int  i0  = (int)tt;
      i0 = i0 < 0 ? 0 : (i0 > 10 ? 10 : i0);
      float u  = tt - (float)i0;
      float um = 1.0f - u;
      float u2 = u * u, u3 = u2 * u;
      float w0 = um * um * um * (1.0f / 6.0f);
      float w1 = (3.0f * u3 - 6.0f * u2 + 4.0f) * (1.0f / 6.0f);
      float w2 = (-3.0f * u3 + 3.0f * u2 + 3.0f * u + 1.0f) * (1.0f / 6.0f);
      float w3 = u3 * (1.0f / 6.0f);
      bool inr = (x >= G0) & (x < G1);

      union { bf16_t hh4[4]; unsigned long long u64; } pk;
      pk.hh4[0] = (bf16_t)w0; pk.hh4[1] = (bf16_t)w1;
      pk.hh4[2] = (bf16_t)w2; pk.hh4[3] = (bf16_t)w3;
      unsigned long long a = inr ? pk.u64 : 0ull;

      int sh = (i0 - 3) * 16;
      unsigned long long lo, hi;
      if (sh >= 0) {
        lo = (sh < 64) ? (a << (sh & 63)) : 0ull;
        hi = (sh == 0) ? 0ull
             : ((sh < 64) ? (a >> ((64 - sh) & 63)) : (a << ((sh - 64) & 63)));
      } else {
        lo = a >> ((-sh) & 63);
        hi = 0ull;
      }
      uint4 wv;
      wv.x = (unsigned)(lo & 0xffffffffull); wv.y = (unsigned)(lo >> 32);
      wv.z = (unsigned)(hi & 0xffffffffull); wv.w = (unsigned)(hi >> 32);
      if (valid) *(uint4*)(abuf + ((h * 128 + idx) << 4)) = wv;
    } else {
      union { bf16_t hh8[8]; bf16x8 v; } pk;
      #pragma unroll
      for (int j = 0; j < 8; ++j) {
        float x = xr[j];
        pk.hh8[j] = (bf16_t)(x / (1.0f + __expf(-x)));
      }
      if (valid) *(bf16x8*)(abuf + ((2 * idx + h) << 4)) = pk.v;
    }
  };

  auto COMPUTE = [&](int cs, const char* bufA, bf16x8 (*BB)[2]) {
    const bool spline = (cs < 32);
    #pragma unroll
    for (int tt = 0; tt < 3; ++tt) if (tt < ntap) {
      const int tap  = tap0 + tt;
      const int ki   = (tap * 11) >> 5;
      const int koff = ki * 12 + (tap - 3 * ki);
      const int c0 = pb0 + koff, c1 = pb1 + koff;
      const int au0 = spline ? (khq + c0) : (2 * c0 + kh);
      const int au1 = spline ? (khq + c1) : (2 * c1 + kh);
      bf16x8 A0f = *(const bf16x8*)(bufA + (au0 << 4));
      bf16x8 A1f = *(const bf16x8*)(bufA + (au1 << 4));
      acc[0][0] = __builtin_amdgcn_mfma_f32_32x32x16_bf16(A0f, BB[tt][0], acc[0][0], 0, 0, 0);
      acc[0][1] = __builtin_amdgcn_mfma_f32_32x32x16_bf16(A0f, BB[tt][1], acc[0][1], 0, 0, 0);
      acc[1][0] = __builtin_amdgcn_mfma_f32_32x32x16_bf16(A1f, BB[tt][0], acc[1][0], 0, 0, 0);
      acc[1][1] = __builtin_amdgcn_mfma_f32_32x32x16_bf16(A1f, BB[tt][1], acc[1][1], 0, 0, 0);
    }
  };

  // ---- prologue: fill chunk 0 (A LDS + B regs), preload x(1) ----
  XLOAD(CS(0), xP);
  WINW(CS(0), xP, Ab0);
  BLOAD(CS(0), BP);
  XLOAD(CS(1), xP);           // xP now holds x(1)
  __syncthreads();

  // ---- main loop: 18 chunks, pair-unrolled so buffer/register roles are static ----
  for (int i = 0; i < 9; ++i) {
    {
      const int k = 2 * i;                 // uses Ab0 / BP
      if (k + 2 < 18) XLOAD(CS(k + 2), xQ);
      if (k + 1 < 18) { BLOAD(CS(k + 1), BQ); WINW(CS(k + 1), xP, Ab1); }
      COMPUTE(CS(k), Ab0, BP);
      __syncthreads();
    }
    {
      const int k = 2 * i + 1;             // uses Ab1 / BQ
      if (k + 2 < 18) XLOAD(CS(k + 2), xP);
      if (k + 1 < 18) { BLOAD(CS(k + 1), BP); WINW(CS(k + 1), xQ, Ab0); }
      COMPUTE(CS(k), Ab1, BQ);
      __syncthreads();
    }
  }

  // ---- staged 4-way reduce in 16KB LDS (3 rounds), then wave 0 atomicAdds ----
  float* red = (float*)smraw;   // 64 x 64 floats = 16KB
  #pragma unroll
  for (int src = 1; src <= 3; ++src) {
    if (w == src) {
      #pragma unroll
      for (int pxt = 0; pxt < 2; ++pxt)
        #pragma unroll
        for (int ot = 0; ot < 2; ++ot)
          #pragma unroll
          for (int q = 0; q < 16; ++q)
            red[(((pxt * 2 + ot) * 16) + q) * 64 + lane] = acc[pxt][ot][q];
    }
    __syncthreads();
    if (w == 0) {
      #pragma unroll
      for (int pxt = 0; pxt < 2; ++pxt)
        #pragma unroll
        for (int ot = 0; ot < 2; ++ot)
          #pragma unroll
          for (int q = 0; q < 16; ++q)
            acc[pxt][ot][q] += red[(((pxt * 2 + ot) * 16) + q) * 64 + lane];
    }
    __syncthreads();
  }

  if (w == 0) {
    #pragma unroll
    for (int pxt = 0; pxt < 2; ++pxt) {
      #pragma unroll
      for (int ot = 0; ot < 2; ++ot) {
        const int o = ot * 32 + r;
        float* obase = out + (((size_t)(img * 64 + o)) << 12);
        #pragma unroll
        for (int g = 0; g < 4; ++g) {
          int px = pxt * 32 + 8 * g + 4 * kh;
          float* ob = obase + (ohb * 8 + (px >> 3)) * 64 + owb * 8 + (px & 7);
          #pragma unroll
          for (int iq = 0; iq < 4; ++iq)
            atomicAdd(ob + iq, acc[pxt][ot][g * 4 + iq]);
        }
      }
    }
  }
}

extern "C" void kernel_launch(void* const* d_in, const int* in_sizes, int n_in,
                              void* d_out, int out_size, void* d_ws, size_t ws_size,
                              hipStream_t stream) {
  const float* x  = (const float*)d_in[0];
  const float* bw = (const float*)d_in[1];
  const float* sw = (const float*)d_in[2];
  const float* ss = (const float*)d_in[3];

  bf16_t* Wf2 = (bf16_t*)d_ws;        // 324*1024*2 = 663,552 B
  float*  o   = (float*)d_out;

  hipMemsetAsync(d_out, 0, (size_t)out_size * sizeof(float), stream);
  prep_w_kernel<<<1296, 256, 0, stream>>>(bw, sw, ss, Wf2);
  convkan_kernel<<<1024, 256, LDS_TOTAL, stream>>>(x, Wf2, o);
}

// Round 16
// 61.280 us; speedup vs baseline: 2.3144x; 2.3144x over previous
//
#include <hip/hip_runtime.h>
#include <stdint.h>

typedef __bf16 bf16_t;
typedef __bf16 bf16x8 __attribute__((ext_vector_type(8)));
typedef float  f32x4  __attribute__((ext_vector_type(4)));
typedef float  f32x16 __attribute__((ext_vector_type(16)));

// LDS: Bb [0,20480) single-buffer (18432 data + 2048 pad), Ab0 [20480,24576),
// Ab1 [24576,28672). Epilogue 16KB reduce unions over Bb.
#define LDS_TOTAL 28672

// ws: Wf2 [0, 663552) ; partials [663552, 663552 + 1024*4096*4)
#define PART_OFF 663552

// async global->LDS, 16B/lane; LDS dest = wave-uniform base + lane*16
__device__ __forceinline__ void gld_lds16(const void* g, void* l) {
  __builtin_amdgcn_global_load_lds(
      (const __attribute__((address_space(1))) uint32_t*)g,
      (__attribute__((address_space(3))) uint32_t*)(uintptr_t)l,
      16, 0, 0);
}

// ---------------- weight repack, step-major + kh-major inner layout (R13/R14-verified) ----------------
// Wf2[s][kh][o][j]  (s=0..323, kh=0..1, o=0..63, j=0..7); element = s*1024 + kh*512 + o*8 + j
__global__ __launch_bounds__(256) void prep_w_kernel(
    const float* __restrict__ bw, const float* __restrict__ sw,
    const float* __restrict__ ss, bf16_t* __restrict__ Wf2) {
  int idx = blockIdx.x * 256 + threadIdx.x;   // < 324*1024 = 331776
  int j = idx & 7, o = (idx >> 3) & 63, kh = (idx >> 9) & 1, s = idx >> 10;
  int kk = kh * 8 + j;
  float v;
  if (s < 288) {
    int q = s / 9, tap = s - q * 9;
    int c = q * 2 + kh;
    int f = c * 9 + tap;
    v = sw[(o * 576 + f) * 8 + j] * ss[o * 576 + f];
  } else {
    int t2 = s - 288;
    int cq = t2 / 9, tap = t2 - cq * 9;
    int c = cq * 16 + kk;
    int f = c * 9 + tap;
    v = bw[o * 576 + f];
  }
  Wf2[idx] = (bf16_t)v;
}

// ---------------- kernel A: grid K-split (parity), partials to ws ----------------
// grid 1024 = 8 img x 64 px-tiles x 2 K-parities. block = 64px x 64och, 18 chunks,
// 4 waves tap-split {0,1}{2,3}{4,5}{6,7,8}. A: LDS dbuf built by VALU (x 2-ahead);
// B: single-buffer 5-uniform DMA; counted vmcnt keeps X prefetch alive.
__global__ __launch_bounds__(256, 2) void convkan_kernel(
    const float* __restrict__ X, const bf16_t* __restrict__ Wf2,
    float* __restrict__ part) {
  extern __shared__ char smraw[];
  char* const Bb  = smraw;
  char* const Ab0 = smraw + 20480;
  char* const Ab1 = smraw + 24576;

  const int t    = threadIdx.x;
  const int lane = t & 63;
  const int w    = t >> 6;        // wave 0..3 (tap group)

  const int b   = blockIdx.x;
  const int rb  = ((b & 7) << 7) | (b >> 3);   // XCD-chunked (1024%8==0, bijective)
  const int img = rb >> 7;
  const int rem = rb & 127;
  const int p   = rem & 1;        // K-parity
  const int tile = rem >> 1;
  const int ohb = tile >> 3, owb = tile & 7;

  // ---- A staging geometry: thread -> (channel-half h, halo cell) on 10x12 grid ----
  const int h   = t >> 7;
  const int idx = t & 127;
  const int row = idx / 12, col = idx - row * 12;
  const bool valid = (idx < 120) && (col < 10);
  const int ih = ohb * 8 + row - 1;
  const int iw = owb * 8 + col - 1;
  const bool inb = valid && ((unsigned)ih < 64u) && ((unsigned)iw < 64u);
  const float* Ximg = X + (((size_t)img * 64) << 12);
  const int   psafe = inb ? ((ih << 6) + iw) : 0;
  const float xmask = inb ? 1.0f : 0.0f;

  // ---- compute-read geometry (verified R9-R15 conventions) ----
  const int r    = lane & 31;
  const int kh   = lane >> 5;
  const int khq  = kh * 128;
  const int pb0  = (r >> 3) * 12 + (r & 7);
  const int pb1  = pb0 + 48;
  const int tap0 = (w < 3) ? (w * 2) : 6;
  const int ntap = (w < 3) ? 2 : 3;

  const float G0 = -2.2f, G1 = 2.2f, INVH = 2.5f;

  f32x16 acc[2][2];
  #pragma unroll
  for (int a = 0; a < 2; ++a)
    #pragma unroll
    for (int c = 0; c < 2; ++c) acc[a][c] = (f32x16)0.0f;

  float xP[8], xQ[8];

  // local chunk k (0..17) -> global chunk id (R15-verified)
  auto CS = [&](int k) { return (k < 16) ? (2 * k + p) : (32 + 2 * (k - 16) + p); };

  auto XLOAD = [&](int cs, float* xr) {
    if (cs < 32) {
      xr[0] = Ximg[(((size_t)(2 * cs + h)) << 12) + psafe] * xmask;   // 1 load
    } else {
      const int c0 = (cs - 32) * 16 + h * 8;
      #pragma unroll
      for (int j = 0; j < 8; ++j)                                      // 8 loads
        xr[j] = Ximg[(((size_t)(c0 + j)) << 12) + psafe] * xmask;
    }
  };

  auto WINW = [&](int cs, const float* xr, char* abuf) {
    if (cs < 32) {
      float x  = xr[0];
      float tt = (x - G0) * INVH;
      int  i0  = (int)tt;
      i0 = i0 < 0 ? 0 : (i0 > 10 ? 10 : i0);
      float u  = tt - (float)i0;
      float um = 1.0f - u;
      float u2 = u * u, u3 = u2 * u;
      float w0 = um * um * um * (1.0f / 6.0f);
      float w1 = (3.0f * u3 - 6.0f * u2 + 4.0f) * (1.0f / 6.0f);
      float w2 = (-3.0f * u3 + 3.0f * u2 + 3.0f * u + 1.0f) * (1.0f / 6.0f);
      float w3 = u3 * (1.0f / 6.0f);
      bool inr = (x >= G0) & (x < G1);

      union { bf16_t hh4[4]; unsigned long long u64; } pk;
      pk.hh4[0] = (bf16_t)w0; pk.hh4[1] = (bf16_t)w1;
      pk.hh4[2] = (bf16_t)w2; pk.hh4[3] = (bf16_t)w3;
      unsigned long long a = inr ? pk.u64 : 0ull;

      int sh = (i0 - 3) * 16;
      unsigned long long lo, hi;
      if (sh >= 0) {
        lo = (sh < 64) ? (a << (sh & 63)) : 0ull;
        hi = (sh == 0) ? 0ull
             : ((sh < 64) ? (a >> ((64 - sh) & 63)) : (a << ((sh - 64) & 63)));
      } else {
        lo = a >> ((-sh) & 63);
        hi = 0ull;
      }
      uint4 wv;
      wv.x = (unsigned)(lo & 0xffffffffull); wv.y = (unsigned)(lo >> 32);
      wv.z = (unsigned)(hi & 0xffffffffull); wv.w = (unsigned)(hi >> 32);
      if (valid) *(uint4*)(abuf + ((h * 128 + idx) << 4)) = wv;
    } else {
      union { bf16_t hh8[8]; bf16x8 v; } pk;
      #pragma unroll
      for (int j = 0; j < 8; ++j) {
        float x = xr[j];
        pk.hh8[j] = (bf16_t)(x / (1.0f + __expf(-x)));
      }
      if (valid) *(bf16x8*)(abuf + ((2 * idx + h) << 4)) = pk.v;
    }
  };

  // every wave issues EXACTLY 5 DMA (vmcnt-uniform); waves 2,3's 5th lands in pad
  auto STAGEB = [&](int cs) {
    const bf16_t* bsrc = Wf2 + (size_t)(cs < 32 ? cs * 9 : 288 + (cs - 32) * 9) * 1024;
    #pragma unroll
    for (int u = 0; u < 4; ++u)
      gld_lds16(bsrc + ((u * 256 + t) << 3), Bb + ((u * 256 + (w << 6)) << 4));
    gld_lds16(bsrc + ((t < 128 ? 1024 + t : t) << 3), Bb + ((1024 + (w << 6)) << 4));
  };

  auto COMPUTE = [&](int cs, const char* bufA) {
    const bool spline = (cs < 32);
    #pragma unroll
    for (int tt = 0; tt < 3; ++tt) if (tt < ntap) {
      const int tap  = tap0 + tt;
      const int ki   = (tap * 11) >> 5;
      const int koff = ki * 12 + (tap - 3 * ki);
      const int c0 = pb0 + koff, c1 = pb1 + koff;
      const int au0 = spline ? (khq + c0) : (2 * c0 + kh);
      const int au1 = spline ? (khq + c1) : (2 * c1 + kh);
      bf16x8 A0f = *(const bf16x8*)(bufA + (au0 << 4));
      bf16x8 A1f = *(const bf16x8*)(bufA + (au1 << 4));
      const char* bt = Bb + (tap << 11) + (kh << 10) + (r << 4);
      bf16x8 B0f = *(const bf16x8*)bt;
      bf16x8 B1f = *(const bf16x8*)(bt + 512);
      acc[0][0] = __builtin_amdgcn_mfma_f32_32x32x16_bf16(A0f, B0f, acc[0][0], 0, 0, 0);
      acc[0][1] = __builtin_amdgcn_mfma_f32_32x32x16_bf16(A0f, B1f, acc[0][1], 0, 0, 0);
      acc[1][0] = __builtin_amdgcn_mfma_f32_32x32x16_bf16(A1f, B0f, acc[1][0], 0, 0, 0);
      acc[1][1] = __builtin_amdgcn_mfma_f32_32x32x16_bf16(A1f, B1f, acc[1][1], 0, 0, 0);
    }
  };

// body for chunk K (K+1 always < 18 here): compute K, then restage B(K+1), prefetch x(K+2)
#define BODY(K, AU, AF, XU, XF, VM, DO_X)                                 \
  do {                                                                     \
    WINW(CS((K) + 1), XU, AF);                                             \
    COMPUTE(CS(K), AU);                                                    \
    asm volatile("s_waitcnt lgkmcnt(0)" ::: "memory");                     \
    __builtin_amdgcn_s_barrier();                                          \
    STAGEB(CS((K) + 1));                                                   \
    __builtin_amdgcn_sched_barrier(0);                                     \
    if (DO_X) XLOAD(CS((K) + 2), XF);                                      \
    __builtin_amdgcn_sched_barrier(0);                                     \
    asm volatile("s_waitcnt vmcnt(" #VM ") lgkmcnt(0)" ::: "memory");      \
    __builtin_amdgcn_s_barrier();                                          \
  } while (0)

  // ---- prologue: fill chunk 0 (A + B), preload x(1) ----
  XLOAD(CS(0), xP);
  WINW(CS(0), xP, Ab0);          // compiler waits x(0) here
  STAGEB(CS(0));
  __builtin_amdgcn_sched_barrier(0);
  XLOAD(CS(1), xP);              // xP now holds x(1)
  __builtin_amdgcn_sched_barrier(0);
  asm volatile("s_waitcnt vmcnt(1) lgkmcnt(0)" ::: "memory");
  __builtin_amdgcn_s_barrier();

  // ---- chunks 0..13 (spline prefetch, 1 X-load) ----
  for (int i = 0; i < 7; ++i) {
    BODY(2 * i,     Ab0, Ab1, xP, xQ, 1, true);
    BODY(2 * i + 1, Ab1, Ab0, xQ, xP, 1, true);
  }
  // chunks 14,15 (silu prefetch, 8 X-loads)
  BODY(14, Ab0, Ab1, xP, xQ, 8, true);
  BODY(15, Ab1, Ab0, xQ, xP, 8, true);
  // chunk 16: stage 17, no prefetch
  BODY(16, Ab0, Ab1, xP, xQ, 0, false);
  // chunk 17: compute only
  COMPUTE(CS(17), Ab1);
#undef BODY

  // ---- staged 4-way reduce in 16KB LDS (3 rounds, R15-verified), partial store ----
  __syncthreads();
  float* red = (float*)smraw;   // 64 x 64 floats = 16KB (unions over Bb)
  #pragma unroll
  for (int src = 1; src <= 3; ++src) {
    if (w == src) {
      #pragma unroll
      for (int pxt = 0; pxt < 2; ++pxt)
        #pragma unroll
        for (int ot = 0; ot < 2; ++ot)
          #pragma unroll
          for (int q = 0; q < 16; ++q)
            red[(((pxt * 2 + ot) * 16) + q) * 64 + lane] = acc[pxt][ot][q];
    }
    __syncthreads();
    if (w == 0) {
      #pragma unroll
      for (int pxt = 0; pxt < 2; ++pxt)
        #pragma unroll
        for (int ot = 0; ot < 2; ++ot)
          #pragma unroll
          for (int q = 0; q < 16; ++q)
            acc[pxt][ot][q] += red[(((pxt * 2 + ot) * 16) + q) * 64 + lane];
    }
    __syncthreads();
  }

  if (w == 0) {
    float* pb = part + ((size_t)rb << 12);   // 4096 floats per block: [o][px]
    #pragma unroll
    for (int pxt = 0; pxt < 2; ++pxt) {
      #pragma unroll
      for (int ot = 0; ot < 2; ++ot) {
        const int o = ot * 32 + r;
        #pragma unroll
        for (int g = 0; g < 4; ++g) {
          int px = pxt * 32 + 8 * g + 4 * kh;
          f32x4 v;
          #pragma unroll
          for (int iq = 0; iq < 4; ++iq) v[iq] = acc[pxt][ot][g * 4 + iq];
          *(f32x4*)(pb + o * 64 + px) = v;
        }
      }
    }
  }
}

// ---------------- kernel B: add the two K-parity partials, write out ----------------
__global__ __launch_bounds__(256) void reduce_kernel(
    const float* __restrict__ part, float* __restrict__ out) {
  int gid = blockIdx.x * 256 + threadIdx.x;     // < 524288
  int ow4 = gid & 15;
  int oh  = (gid >> 4) & 63;
  int o   = (gid >> 10) & 63;
  int img = gid >> 16;
  int tile = ((oh >> 3) << 3) | (ow4 >> 1);
  int px4  = ((oh & 7) << 3) | ((ow4 & 1) << 2);
  size_t base = (((size_t)((img << 7) | (tile << 1))) << 12) + o * 64 + px4;
  f32x4 a = *(const f32x4*)(part + base);
  f32x4 b = *(const f32x4*)(part + base + 4096);
  *(f32x4*)(out + (size_t)gid * 4) = a + b;
}

extern "C" void kernel_launch(void* const* d_in, const int* in_sizes, int n_in,
                              void* d_out, int out_size, void* d_ws, size_t ws_size,
                              hipStream_t stream) {
  const float* x  = (const float*)d_in[0];
  const float* bw = (const float*)d_in[1];
  const float* sw = (const float*)d_in[2];
  const float* ss = (const float*)d_in[3];

  char* ws = (char*)d_ws;
  bf16_t* Wf2  = (bf16_t*)ws;                 // 663,552 B
  float*  part = (float*)(ws + PART_OFF);     // 16,777,216 B
  float*  o    = (float*)d_out;

  prep_w_kernel<<<1296, 256, 0, stream>>>(bw, sw, ss, Wf2);
  convkan_kernel<<<1024, 256, LDS_TOTAL, stream>>>(x, Wf2, part);
  reduce_kernel<<<2048, 256, 0, stream>>>(part, o);
}

// Round 17
// 54.479 us; speedup vs baseline: 2.6033x; 1.1248x over previous
//
#include <hip/hip_runtime.h>
#include <stdint.h>

typedef __bf16 bf16_t;
typedef __bf16 bf16x8 __attribute__((ext_vector_type(8)));
typedef float  f32x4  __attribute__((ext_vector_type(4)));
typedef float  f32x16 __attribute__((ext_vector_type(16)));

// LDS: Ab0 [0,4096) Ab1 [4096,8192); staged epilogue reduce (16KB) unions from 0
#define LDS_TOTAL 16384

// ws: Wf2 [0, 663552) ; partials [663552, +1024*4096*4)
#define PART_OFF 663552

// ---------------- weight repack, step-major + kh-major inner layout (R13-R16 verified) ----------------
// Wf2[s][kh][o][j]  (s=0..323, kh=0..1, o=0..63, j=0..7); element = s*1024 + kh*512 + o*8 + j
__global__ __launch_bounds__(256) void prep_w_kernel(
    const float* __restrict__ bw, const float* __restrict__ sw,
    const float* __restrict__ ss, bf16_t* __restrict__ Wf2) {
  int idx = blockIdx.x * 256 + threadIdx.x;   // < 324*1024 = 331776
  int j = idx & 7, o = (idx >> 3) & 63, kh = (idx >> 9) & 1, s = idx >> 10;
  int kk = kh * 8 + j;
  float v;
  if (s < 288) {
    int q = s / 9, tap = s - q * 9;
    int c = q * 2 + kh;
    int f = c * 9 + tap;
    v = sw[(o * 576 + f) * 8 + j] * ss[o * 576 + f];
  } else {
    int t2 = s - 288;
    int cq = t2 / 9, tap = t2 - cq * 9;
    int c = cq * 16 + kk;
    int f = c * 9 + tap;
    v = bw[o * 576 + f];
  }
  Wf2[idx] = (bf16_t)v;
}

// ---------------- kernel A: grid K-parity split, A in LDS, B in registers ----------------
// grid 1024 = 8 img x 64 px-tiles x 2 K-parities. block = 64px x 64och, 18 chunks;
// 4 waves tap-split {0,1}{2,3}{4,5}{6,7,8}. A: LDS dbuf built by VALU (x 2-ahead);
// B: register dbuf BP/BQ from L2, 1 chunk ahead. Partials to ws; no atomics.
__global__ __launch_bounds__(256, 3) void convkan_kernel(
    const float* __restrict__ X, const bf16_t* __restrict__ Wf2,
    float* __restrict__ part) {
  extern __shared__ char smraw[];
  char* const Ab0 = smraw;
  char* const Ab1 = smraw + 4096;

  const int t    = threadIdx.x;
  const int lane = t & 63;
  const int w    = t >> 6;        // wave 0..3 (tap group)

  const int b   = blockIdx.x;
  const int rb  = ((b & 7) << 7) | (b >> 3);   // XCD-chunked (1024%8==0, bijective)
  const int img = rb >> 7;
  const int rem = rb & 127;
  const int p   = rem & 1;        // K-parity
  const int tile = rem >> 1;
  const int ohb = tile >> 3, owb = tile & 7;

  // ---- A staging geometry: thread -> (channel-half h, halo cell) on 10x12 grid ----
  const int h   = t >> 7;
  const int idx = t & 127;
  const int row = idx / 12, col = idx - row * 12;
  const bool valid = (idx < 120) && (col < 10);
  const int ih = ohb * 8 + row - 1;
  const int iw = owb * 8 + col - 1;
  const bool inb = valid && ((unsigned)ih < 64u) && ((unsigned)iw < 64u);
  const float* Ximg = X + (((size_t)img * 64) << 12);
  const int   psafe = inb ? ((ih << 6) + iw) : 0;   // clamped: loads always issue
  const float xmask = inb ? 1.0f : 0.0f;

  // ---- compute-read geometry (verified R9-R16 conventions) ----
  const int r    = lane & 31;
  const int kh   = lane >> 5;
  const int khq  = kh * 128;
  const int pb0  = (r >> 3) * 12 + (r & 7);
  const int pb1  = pb0 + 48;
  const int tap0 = (w < 3) ? (w * 2) : 6;
  const int ntap = (w < 3) ? 2 : 3;

  const float G0 = -2.2f, G1 = 2.2f, INVH = 2.5f;

  f32x16 acc[2][2];
  #pragma unroll
  for (int a = 0; a < 2; ++a)
    #pragma unroll
    for (int c = 0; c < 2; ++c) acc[a][c] = (f32x16)0.0f;

  float xP[8], xQ[8];
  bf16x8 BP[3][2], BQ[3][2];      // per-tap B frags, double-buffered (static idx only)

  // local chunk k (0..17) -> global chunk id (R15/R16-verified)
  auto CS = [&](int k) { return (k < 16) ? (2 * k + p) : (32 + 2 * (k - 16) + p); };

  auto XLOAD = [&](int cs, float* xr) {
    if (cs < 32) {
      xr[0] = Ximg[(((size_t)(2 * cs + h)) << 12) + psafe] * xmask;   // 1 load
    } else {
      const int c0 = (cs - 32) * 16 + h * 8;
      #pragma unroll
      for (int j = 0; j < 8; ++j)                                      // 8 loads
        xr[j] = Ximg[(((size_t)(c0 + j)) << 12) + psafe] * xmask;
    }
  };

  // per-lane coalesced B loads (R14-verified): elem = s*1024 + kh*512 + r*8 (+256 tile1)
  auto BLOAD = [&](int cs, bf16x8 (*BB)[2]) {
    const int sb = (cs < 32) ? cs * 9 : 288 + (cs - 32) * 9;
    #pragma unroll
    for (int tt = 0; tt < 3; ++tt) if (tt < ntap) {
      const bf16_t* pp = Wf2 + (((size_t)(sb + tap0 + tt)) << 10) + (kh << 9) + (r << 3);
      BB[tt][0] = *(const bf16x8*)pp;
      BB[tt][1] = *(const bf16x8*)(pp + 256);
    }
  };

  auto WINW = [&](int cs, const float* xr, char* abuf) {
    if (cs < 32) {
      // uniform cubic B-spline window (verified R1-R16)
      float x  = xr[0];
      float tt = (x - G0) * INVH;
      int  i0  = (int)tt;
      i0 = i0 < 0 ? 0 : (i0 > 10 ? 10 : i0);
      float u  = tt - (float)i0;
      float um = 1.0f - u;
      float u2 = u * u, u3 = u2 * u;
      float w0 = um * um * um * (1.0f / 6.0f);
      float w1 = (3.0f * u3 - 6.0f * u2 + 4.0f) * (1.0f / 6.0f);
      float w2 = (-3.0f * u3 + 3.0f * u2 + 3.0f * u + 1.0f) * (1.0f / 6.0f);
      float w3 = u3 * (1.0f / 6.0f);
      bool inr = (x >= G0) & (x < G1);

      union { bf16_t hh4[4]; unsigned long long u64; } pk;
      pk.hh4[0] = (bf16_t)w0; pk.hh4[1] = (bf16_t)w1;
      pk.hh4[2] = (bf16_t)w2; pk.hh4[3] = (bf16_t)w3;
      unsigned long long a = inr ? pk.u64 : 0ull;

      int sh = (i0 - 3) * 16;
      unsigned long long lo, hi;
      if (sh >= 0) {
        lo = (sh < 64) ? (a << (sh & 63)) : 0ull;
        hi = (sh == 0) ? 0ull
             : ((sh < 64) ? (a >> ((64 - sh) & 63)) : (a << ((sh - 64) & 63)));
      } else {
        lo = a >> ((-sh) & 63);
        hi = 0ull;
      }
      uint4 wv;
      wv.x = (unsigned)(lo & 0xffffffffull); wv.y = (unsigned)(lo >> 32);
      wv.z = (unsigned)(hi & 0xffffffffull); wv.w = (unsigned)(hi >> 32);
      if (valid) *(uint4*)(abuf + ((h * 128 + idx) << 4)) = wv;
    } else {
      union { bf16_t hh8[8]; bf16x8 v; } pk;
      #pragma unroll
      for (int j = 0; j < 8; ++j) {
        float x = xr[j];
        pk.hh8[j] = (bf16_t)(x / (1.0f + __expf(-x)));
      }
      if (valid) *(bf16x8*)(abuf + ((2 * idx + h) << 4)) = pk.v;
    }
  };

  auto COMPUTE = [&](int cs, const char* bufA, bf16x8 (*BB)[2]) {
    const bool spline = (cs < 32);
    #pragma unroll
    for (int tt = 0; tt < 3; ++tt) if (tt < ntap) {
      const int tap  = tap0 + tt;
      const int ki   = (tap * 11) >> 5;
      const int koff = ki * 12 + (tap - 3 * ki);
      const int c0 = pb0 + koff, c1 = pb1 + koff;
      const int au0 = spline ? (khq + c0) : (2 * c0 + kh);
      const int au1 = spline ? (khq + c1) : (2 * c1 + kh);
      bf16x8 A0f = *(const bf16x8*)(bufA + (au0 << 4));
      bf16x8 A1f = *(const bf16x8*)(bufA + (au1 << 4));
      acc[0][0] = __builtin_amdgcn_mfma_f32_32x32x16_bf16(A0f, BB[tt][0], acc[0][0], 0, 0, 0);
      acc[0][1] = __builtin_amdgcn_mfma_f32_32x32x16_bf16(A0f, BB[tt][1], acc[0][1], 0, 0, 0);
      acc[1][0] = __builtin_amdgcn_mfma_f32_32x32x16_bf16(A1f, BB[tt][0], acc[1][0], 0, 0, 0);
      acc[1][1] = __builtin_amdgcn_mfma_f32_32x32x16_bf16(A1f, BB[tt][1], acc[1][1], 0, 0, 0);
    }
  };

  // ---- prologue: fill chunk 0 (A LDS + B regs), preload x(1) ----
  XLOAD(CS(0), xP);
  WINW(CS(0), xP, Ab0);
  BLOAD(CS(0), BP);
  XLOAD(CS(1), xP);           // xP now holds x(1)
  __syncthreads();

  // ---- main loop: 18 chunks, pair-unrolled so buffer/register roles are static ----
  for (int i = 0; i < 9; ++i) {
    {
      const int k = 2 * i;                 // uses Ab0 / BP
      if (k + 2 < 18) XLOAD(CS(k + 2), xQ);
      if (k + 1 < 18) { BLOAD(CS(k + 1), BQ); WINW(CS(k + 1), xP, Ab1); }
      COMPUTE(CS(k), Ab0, BP);
      __syncthreads();
    }
    {
      const int k = 2 * i + 1;             // uses Ab1 / BQ
      if (k + 2 < 18) XLOAD(CS(k + 2), xP);
      if (k + 1 < 18) { BLOAD(CS(k + 1), BP); WINW(CS(k + 1), xQ, Ab0); }
      COMPUTE(CS(k), Ab1, BQ);
      __syncthreads();
    }
  }

  // ---- staged 4-way reduce in 16KB LDS (3 rounds, R15/R16-verified) ----
  float* red = (float*)smraw;   // 64 x 64 floats = 16KB
  #pragma unroll
  for (int src = 1; src <= 3; ++src) {
    if (w == src) {
      #pragma unroll
      for (int pxt = 0; pxt < 2; ++pxt)
        #pragma unroll
        for (int ot = 0; ot < 2; ++ot)
          #pragma unroll
          for (int q = 0; q < 16; ++q)
            red[(((pxt * 2 + ot) * 16) + q) * 64 + lane] = acc[pxt][ot][q];
    }
    __syncthreads();
    if (w == 0) {
      #pragma unroll
      for (int pxt = 0; pxt < 2; ++pxt)
        #pragma unroll
        for (int ot = 0; ot < 2; ++ot)
          #pragma unroll
          for (int q = 0; q < 16; ++q)
            acc[pxt][ot][q] += red[(((pxt * 2 + ot) * 16) + q) * 64 + lane];
    }
    __syncthreads();
  }

  // ---- partial store (plain coalesced f32x4, R16-verified layout) ----
  if (w == 0) {
    float* pb = part + ((size_t)rb << 12);   // 4096 floats per block: [o][px]
    #pragma unroll
    for (int pxt = 0; pxt < 2; ++pxt) {
      #pragma unroll
      for (int ot = 0; ot < 2; ++ot) {
        const int o = ot * 32 + r;
        #pragma unroll
        for (int g = 0; g < 4; ++g) {
          int px = pxt * 32 + 8 * g + 4 * kh;
          f32x4 v;
          #pragma unroll
          for (int iq = 0; iq < 4; ++iq) v[iq] = acc[pxt][ot][g * 4 + iq];
          *(f32x4*)(pb + o * 64 + px) = v;
        }
      }
    }
  }
}

// ---------------- kernel B: add the two K-parity partials, write out (R16-verified) ----------------
__global__ __launch_bounds__(256) void reduce_kernel(
    const float* __restrict__ part, float* __restrict__ out) {
  int gid = blockIdx.x * 256 + threadIdx.x;     // < 524288
  int ow4 = gid & 15;
  int oh  = (gid >> 4) & 63;
  int o   = (gid >> 10) & 63;
  int img = gid >> 16;
  int tile = ((oh >> 3) << 3) | (ow4 >> 1);
  int px4  = ((oh & 7) << 3) | ((ow4 & 1) << 2);
  size_t base = (((size_t)((img << 7) | (tile << 1))) << 12) + o * 64 + px4;
  f32x4 a = *(const f32x4*)(part + base);
  f32x4 b = *(const f32x4*)(part + base + 4096);
  *(f32x4*)(out + (size_t)gid * 4) = a + b;
}

extern "C" void kernel_launch(void* const* d_in, const int* in_sizes, int n_in,
                              void* d_out, int out_size, void* d_ws, size_t ws_size,
                              hipStream_t stream) {
  const float* x  = (const float*)d_in[0];
  const float* bw = (const float*)d_in[1];
  const float* sw = (const float*)d_in[2];
  const float* ss = (const float*)d_in[3];

  char* ws = (char*)d_ws;
  bf16_t* Wf2  = (bf16_t*)ws;                 // 663,552 B
  float*  part = (float*)(ws + PART_OFF);     // 16,777,216 B
  float*  o    = (float*)d_out;

  prep_w_kernel<<<1296, 256, 0, stream>>>(bw, sw, ss, Wf2);
  convkan_kernel<<<1024, 256, LDS_TOTAL, stream>>>(x, Wf2, part);
  reduce_kernel<<<2048, 256, 0, stream>>>(part, o);
}

// Round 18
// 39.813 us; speedup vs baseline: 3.5624x; 1.3684x over previous
//
#include <hip/hip_runtime.h>
#include <stdint.h>

typedef __bf16 bf16_t;
typedef __bf16 bf16x8 __attribute__((ext_vector_type(8)));
typedef float  f32x4  __attribute__((ext_vector_type(4)));
typedef float  f32x16 __attribute__((ext_vector_type(16)));

// LDS: Ab0 [0,16384) Ab1 [16384,32768); epilogue reduce (48KB) unions from 0
#define LDS_TOTAL 49152

// ---------------- weight repack, step-major + kh-major inner layout (R13-R17 verified) ----------------
// Wf2[s][kh][o][j]  (s=0..323, kh=0..1, o=0..63, j=0..7); element = s*1024 + kh*512 + o*8 + j
__global__ __launch_bounds__(256) void prep_w_kernel(
    const float* __restrict__ bw, const float* __restrict__ sw,
    const float* __restrict__ ss, bf16_t* __restrict__ Wf2) {
  int idx = blockIdx.x * 256 + threadIdx.x;   // < 324*1024 = 331776
  int j = idx & 7, o = (idx >> 3) & 63, kh = (idx >> 9) & 1, s = idx >> 10;
  int kk = kh * 8 + j;
  float v;
  if (s < 288) {
    int q = s / 9, tap = s - q * 9;
    int c = q * 2 + kh;
    int f = c * 9 + tap;
    v = sw[(o * 576 + f) * 8 + j] * ss[o * 576 + f];
  } else {
    int t2 = s - 288;
    int cq = t2 / 9, tap = t2 - cq * 9;
    int c = cq * 16 + kk;
    int f = c * 9 + tap;
    v = bw[o * 576 + f];
  }
  Wf2[idx] = (bf16_t)v;
}

// ---------------- main fused kernel: balanced per-wave K ownership ----------------
// grid 512 = 8 img x 64 px-tiles. block = 64px x 64och, 4 waves.
// 9 chunks: k=0..7 spline (4 ch-pairs each; wave w owns pair k*4+w, all 9 taps),
//           k=8 silu (wave w owns quad w, all 9 taps). Perfectly balanced.
// A: LDS dbuf built by VALU (per-pair sub-buffers, verified layout).
// B: per-wave contiguous 18KB slice of Wf2 -> registers BB[9][2], loaded at chunk top.
__global__ __launch_bounds__(256, 2) void convkan_kernel(
    const float* __restrict__ X, const bf16_t* __restrict__ Wf2,
    float* __restrict__ out) {
  extern __shared__ char smraw[];
  char* const Ab0 = smraw;
  char* const Ab1 = smraw + 16384;

  const int t    = threadIdx.x;
  const int lane = t & 63;
  const int w    = t >> 6;        // wave 0..3: owns ch-pair (k*4+w) / silu quad w

  const int b   = blockIdx.x;
  const int rb  = ((b & 7) << 6) | (b >> 3);   // XCD-chunked (512%8==0, bijective)
  const int img = rb >> 6;
  const int rem = rb & 63;
  const int ohb = rem >> 3, owb = rem & 7;

  // ---- A staging geometry: thread -> (channel-half h, halo cell) on 10x12 grid ----
  const int h   = t >> 7;
  const int idx = t & 127;
  const int row = idx / 12, col = idx - row * 12;
  const bool valid = (idx < 120) && (col < 10);
  const int ih = ohb * 8 + row - 1;
  const int iw = owb * 8 + col - 1;
  const bool inb = valid && ((unsigned)ih < 64u) && ((unsigned)iw < 64u);
  const float* Ximg = X + (((size_t)img * 64) << 12);
  const int   psafe = inb ? ((ih << 6) + iw) : 0;   // clamped: loads always issue
  const float xmask = inb ? 1.0f : 0.0f;

  // ---- compute-read geometry (verified R9-R17 conventions) ----
  const int r    = lane & 31;
  const int kh   = lane >> 5;
  const int khq  = kh * 128;
  const int pb0  = (r >> 3) * 12 + (r & 7);
  const int pb1  = pb0 + 48;

  const float G0 = -2.2f, G1 = 2.2f, INVH = 2.5f;

  f32x16 acc[2][2];
  #pragma unroll
  for (int a = 0; a < 2; ++a)
    #pragma unroll
    for (int c = 0; c < 2; ++c) acc[a][c] = (f32x16)0.0f;

  float xP[4], xQ[4];
  bf16x8 BB[9][2];               // this chunk's B slice (static indices only)

  // x loads for spline chunk k: 4 pairs, this thread's channel = pair*2 + h
  auto XLOADSP = [&](int k, float* xr) {
    #pragma unroll
    for (int cp = 0; cp < 4; ++cp) {
      int ch = (k * 4 + cp) * 2 + h;
      xr[cp] = Ximg[(((size_t)ch) << 12) + psafe] * xmask;
    }
  };

  // spline windows for 4 pairs -> per-pair sub-buffers (verified window math)
  auto WINWSP = [&](const float* xr, char* abuf) {
    #pragma unroll
    for (int cp = 0; cp < 4; ++cp) {
      float x  = xr[cp];
      float tt = (x - G0) * INVH;
      int  i0  = (int)tt;
      i0 = i0 < 0 ? 0 : (i0 > 10 ? 10 : i0);
      float u  = tt - (float)i0;
      float um = 1.0f - u;
      float u2 = u * u, u3 = u2 * u;
      float w0 = um * um * um * (1.0f / 6.0f);
      float w1 = (3.0f * u3 - 6.0f * u2 + 4.0f) * (1.0f / 6.0f);
      float w2 = (-3.0f * u3 + 3.0f * u2 + 3.0f * u + 1.0f) * (1.0f / 6.0f);
      float w3 = u3 * (1.0f / 6.0f);
      bool inr = (x >= G0) & (x < G1);

      union { bf16_t hh4[4]; unsigned long long u64; } pk;
      pk.hh4[0] = (bf16_t)w0; pk.hh4[1] = (bf16_t)w1;
      pk.hh4[2] = (bf16_t)w2; pk.hh4[3] = (bf16_t)w3;
      unsigned long long a = inr ? pk.u64 : 0ull;

      int sh = (i0 - 3) * 16;
      unsigned long long lo, hi;
      if (sh >= 0) {
        lo = (sh < 64) ? (a << (sh & 63)) : 0ull;
        hi = (sh == 0) ? 0ull
             : ((sh < 64) ? (a >> ((64 - sh) & 63)) : (a << ((sh - 64) & 63)));
      } else {
        lo = a >> ((-sh) & 63);
        hi = 0ull;
      }
      uint4 wv;
      wv.x = (unsigned)(lo & 0xffffffffull); wv.y = (unsigned)(lo >> 32);
      wv.z = (unsigned)(hi & 0xffffffffull); wv.w = (unsigned)(hi >> 32);
      if (valid) *(uint4*)(abuf + (cp << 12) + ((h * 128 + idx) << 4)) = wv;
    }
  };

  // B: wave's contiguous slice, 9 taps x 2 och-tiles (coalesced 16B/lane)
  auto BLOADK = [&](int k) {
    const int s0 = (k < 8) ? (k * 4 + w) * 9 : 288 + w * 9;
    #pragma unroll
    for (int tap = 0; tap < 9; ++tap) {
      const bf16_t* pp = Wf2 + (((size_t)(s0 + tap)) << 10) + (kh << 9) + (r << 3);
      BB[tap][0] = *(const bf16x8*)pp;
      BB[tap][1] = *(const bf16x8*)(pp + 256);
    }
  };

  auto COMPUTEK = [&](int k, const char* bufA) {
    const bool spline = (k < 8);
    #pragma unroll
    for (int tap = 0; tap < 9; ++tap) {
      const int ki   = (tap * 11) >> 5;
      const int koff = ki * 12 + (tap - 3 * ki);
      const int c0 = pb0 + koff, c1 = pb1 + koff;
      const char* a0p = spline ? (bufA + (w << 12) + ((khq + c0) << 4))
                               : (bufA + (c0 << 7) + (w << 5) + (kh << 4));
      const char* a1p = spline ? (bufA + (w << 12) + ((khq + c1) << 4))
                               : (bufA + (c1 << 7) + (w << 5) + (kh << 4));
      bf16x8 A0f = *(const bf16x8*)a0p;
      bf16x8 A1f = *(const bf16x8*)a1p;
      acc[0][0] = __builtin_amdgcn_mfma_f32_32x32x16_bf16(A0f, BB[tap][0], acc[0][0], 0, 0, 0);
      acc[0][1] = __builtin_amdgcn_mfma_f32_32x32x16_bf16(A0f, BB[tap][1], acc[0][1], 0, 0, 0);
      acc[1][0] = __builtin_amdgcn_mfma_f32_32x32x16_bf16(A1f, BB[tap][0], acc[1][0], 0, 0, 0);
      acc[1][1] = __builtin_amdgcn_mfma_f32_32x32x16_bf16(A1f, BB[tap][1], acc[1][1], 0, 0, 0);
    }
  };

  // ---- prologue: stage chunk 0, preload x(1) ----
  XLOADSP(0, xP);
  WINWSP(xP, Ab0);
  XLOADSP(1, xP);             // xP now holds x(chunk 1)
  __syncthreads();

  // ---- spline chunks 0..7, pair-unrolled (static buffer/x roles) ----
  #pragma unroll
  for (int i = 0; i < 4; ++i) {
    {
      const int k = 2 * i;                 // computes Ab0
      BLOADK(k);
      if (k + 2 < 8) XLOADSP(k + 2, xQ);
      WINWSP(xP, Ab1);                     // stages chunk k+1
      COMPUTEK(k, Ab0);
      __syncthreads();
    }
    {
      const int k = 2 * i + 1;             // computes Ab1
      BLOADK(k);
      if (k + 2 < 8) XLOADSP(k + 2, xP);
      if (k + 1 < 8) WINWSP(xQ, Ab0);      // k=7: next is silu, staged below
      COMPUTEK(k, Ab1);
      __syncthreads();
    }
  }

  // ---- silu chunk (k=8): stage 64 ch cell-major into Ab0, then compute ----
  {
    #pragma unroll
    for (int q = 0; q < 4; ++q) {
      const int c0 = q * 16 + h * 8;
      union { bf16_t hh8[8]; bf16x8 v; } pk;
      #pragma unroll
      for (int j = 0; j < 8; ++j) {
        float x = Ximg[(((size_t)(c0 + j)) << 12) + psafe] * xmask;
        pk.hh8[j] = (bf16_t)(x / (1.0f + __expf(-x)));
      }
      if (valid) *(bf16x8*)(Ab0 + (idx << 7) + (q << 5) + (h << 4)) = pk.v;
    }
    __syncthreads();
    BLOADK(8);
    COMPUTEK(8, Ab0);
  }

  // ---- 4-way K-reduce: waves 1-3 dump, wave 0 combines + stores (R13 verbatim) ----
  __syncthreads();
  float* red = (float*)smraw;
  if (w != 0) {
    #pragma unroll
    for (int pxt = 0; pxt < 2; ++pxt)
      #pragma unroll
      for (int ot = 0; ot < 2; ++ot)
        #pragma unroll
        for (int q = 0; q < 16; ++q)
          red[(((w - 1) * 64) + (pxt * 2 + ot) * 16 + q) * 64 + lane] = acc[pxt][ot][q];
  }
  __syncthreads();
  if (w == 0) {
    #pragma unroll
    for (int pxt = 0; pxt < 2; ++pxt) {
      #pragma unroll
      for (int ot = 0; ot < 2; ++ot) {
        const int o = ot * 32 + r;
        float* obase = out + (((size_t)(img * 64 + o)) << 12);
        #pragma unroll
        for (int g = 0; g < 4; ++g) {
          f32x4 v;
          #pragma unroll
          for (int iq = 0; iq < 4; ++iq) {
            int q = g * 4 + iq;
            int ri = (pxt * 2 + ot) * 16 + q;
            v[iq] = acc[pxt][ot][q]
                  + red[(0 * 64 + ri) * 64 + lane]
                  + red[(1 * 64 + ri) * 64 + lane]
                  + red[(2 * 64 + ri) * 64 + lane];
          }
          int px = pxt * 32 + 8 * g + 4 * kh;
          *(f32x4*)(obase + (ohb * 8 + (px >> 3)) * 64 + owb * 8 + (px & 7)) = v;
        }
      }
    }
  }
}

extern "C" void kernel_launch(void* const* d_in, const int* in_sizes, int n_in,
                              void* d_out, int out_size, void* d_ws, size_t ws_size,
                              hipStream_t stream) {
  const float* x  = (const float*)d_in[0];
  const float* bw = (const float*)d_in[1];
  const float* sw = (const float*)d_in[2];
  const float* ss = (const float*)d_in[3];

  bf16_t* Wf2 = (bf16_t*)d_ws;        // 324*1024*2 = 663,552 B
  float*  o   = (float*)d_out;

  prep_w_kernel<<<1296, 256, 0, stream>>>(bw, sw, ss, Wf2);
  convkan_kernel<<<512, 256, LDS_TOTAL, stream>>>(x, Wf2, o);
}